// Round 3
// baseline (464.751 us; speedup 1.0000x reference)
//
#include <hip/hip_runtime.h>
#include <cstdint>
#include <cstddef>

// ---------- constants for this problem ----------
#define S_LEN 2048
#define HID 4096
#define NH 32
#define NKV 8
#define HD 128

typedef __attribute__((ext_vector_type(4))) float f32x4;
typedef __attribute__((ext_vector_type(8))) short bf16x8;

__device__ __forceinline__ unsigned short f2bf(float f) {
  union { float f; uint32_t u; } v; v.f = f;
  uint32_t r = v.u + 0x7FFFu + ((v.u >> 16) & 1u);  // round-to-nearest-even
  return (unsigned short)(r >> 16);
}

__device__ __forceinline__ float exp2_fast(float x) {
#if __has_builtin(__builtin_amdgcn_exp2f)
  return __builtin_amdgcn_exp2f(x);
#else
  float r; asm("v_exp_f32 %0, %1" : "=v"(r) : "v"(x)); return r;
#endif
}

// pack two f32 -> one u32 of 2x bf16 (RNE) via hw instruction (T12 recipe)
__device__ __forceinline__ unsigned int cvt_pk_bf16(float lo, float hi) {
  unsigned int r;
  asm("v_cvt_pk_bf16_f32 %0, %1, %2" : "=v"(r) : "v"(lo), "v"(hi));
  return r;
}

// ---------- fp32 -> bf16 straight cast (vectorized x4) ----------
__global__ void cvt_bf16_kernel(const float* __restrict__ in,
                                unsigned short* __restrict__ out, int n4) {
  int i = blockIdx.x * blockDim.x + threadIdx.x;
  if (i >= n4) return;
  float4 v = ((const float4*)in)[i];
  ushort4 o;
  o.x = f2bf(v.x); o.y = f2bf(v.y); o.z = f2bf(v.z); o.w = f2bf(v.w);
  ((ushort4*)out)[i] = o;
}

// ---------- fp32 [b][R][C] -> bf16 [b][C][R] transpose-cast, 64x64 tiles ----------
__global__ __launch_bounds__(256) void transpose_cvt2_kernel(
    const float* __restrict__ in0, unsigned short* __restrict__ out0,
    const float* __restrict__ in1, unsigned short* __restrict__ out1,
    int R, int C) {
  __shared__ float tile[64][65];
  const float* inb = (blockIdx.z == 0) ? in0 : in1;
  unsigned short* outb = (blockIdx.z == 0) ? out0 : out1;
  const int c0 = blockIdx.x * 64, r0 = blockIdx.y * 64;
  const int tid = threadIdx.x;
#pragma unroll
  for (int p = 0; p < 4; ++p) {
    const int ch = p * 256 + tid;
    const int r = ch >> 4, off = (ch & 15) << 2;
    *(float4*)&tile[r][off] = *(const float4*)(inb + (size_t)(r0 + r) * C + c0 + off);
  }
  __syncthreads();
#pragma unroll
  for (int p = 0; p < 2; ++p) {
    const int ch = p * 256 + tid;
    const int i = ch >> 3, j0 = (ch & 7) << 3;
    bf16x8 v;
#pragma unroll
    for (int k = 0; k < 8; ++k) v[k] = (short)f2bf(tile[j0 + k][i]);
    *(bf16x8*)(outb + (size_t)(c0 + i) * R + r0 + j0) = v;
  }
}

// per-batch variant for v_cache [NKV][S][HD] -> [NKV][HD][S]
__global__ __launch_bounds__(256) void transpose_cvt_kernel(
    const float* __restrict__ in, unsigned short* __restrict__ out, int R, int C) {
  __shared__ float tile[64][65];
  const int b = blockIdx.z;
  const float* inb = in + (size_t)b * R * C;
  unsigned short* outb = out + (size_t)b * R * C;
  const int c0 = blockIdx.x * 64, r0 = blockIdx.y * 64;
  const int tid = threadIdx.x;
#pragma unroll
  for (int p = 0; p < 4; ++p) {
    const int ch = p * 256 + tid;
    const int r = ch >> 4, off = (ch & 15) << 2;
    *(float4*)&tile[r][off] = *(const float4*)(inb + (size_t)(r0 + r) * C + c0 + off);
  }
  __syncthreads();
#pragma unroll
  for (int p = 0; p < 2; ++p) {
    const int ch = p * 256 + tid;
    const int i = ch >> 3, j0 = (ch & 7) << 3;
    bf16x8 v;
#pragma unroll
    for (int k = 0; k < 8; ++k) v[k] = (short)f2bf(tile[j0 + k][i]);
    *(bf16x8*)(outb + (size_t)(c0 + i) * R + r0 + j0) = v;
  }
}

// ---------- bf16 GEMM v2: 128x256 tile, 8 waves, tri-buffer counted-vmcnt ----------
// T3/T4: 3 LDS buffers, 2-deep prefetch, steady-state s_waitcnt vmcnt(6) (never 0
// in the loop). ONE raw s_barrier per K-tile; stage(t+2) issued after it (the
// barrier proves all waves retired their buf(t-1) ds_reads = the overwrite target).
// Retirement order: outstanding at top of t = stage(t)[6]+stage(t+1)[6]; vmcnt(6)
// completes exactly stage(t). T5 setprio around MFMA clusters. T2 chunk-XOR layout
// and fragment math identical to the proven 128^2 kernel.
__global__ __launch_bounds__(512, 2) void gemm_bt_kernel(
    const unsigned short* __restrict__ A, const unsigned short* __restrict__ BT,
    float* __restrict__ C, int M, int N, int K) {
  __shared__ __align__(16) unsigned short As[3][128 * 64];
  __shared__ __align__(16) unsigned short Bs[3][256 * 64];
  const int tid = threadIdx.x;
  const int lane = tid & 63;
  const int wid = tid >> 6;               // 0..7
  const int wm = (wid >> 2) * 64;         // 2 M-waves x 64
  const int wn = (wid & 3) * 64;          // 4 N-waves x 64
  const int g = blockIdx.x;
  const int wg = (g & 7) * 32 + (g >> 3); // bijective XCD chunk map (nwg=256)
  const int m0 = (wg & 15) * 128;         // n-major per XCD: B-panels stay in L2
  const int n0 = (wg >> 4) * 256;
  const int lr = lane & 15;
  const int quad = lane >> 4;
  const int sw = lr & 7;
  const int nkt = K >> 6;

  auto stage = [&](int buf, int kt) {
#pragma unroll
    for (int p = 0; p < 2; ++p) {
      const int c = p * 512 + tid;          // A chunks 0..1023 (16B)
      const int r = c >> 3, j = (c & 7) ^ (r & 7);
      __builtin_amdgcn_global_load_lds(
          (const __attribute__((address_space(1))) void*)(A + (size_t)(m0 + r) * K + kt * 64 + j * 8),
          (__attribute__((address_space(3))) void*)(&As[buf][c * 8]), 16, 0, 0);
    }
#pragma unroll
    for (int p = 0; p < 4; ++p) {
      const int c = p * 512 + tid;          // B chunks 0..2047
      const int r = c >> 3, j = (c & 7) ^ (r & 7);
      __builtin_amdgcn_global_load_lds(
          (const __attribute__((address_space(1))) void*)(BT + (size_t)(n0 + r) * K + kt * 64 + j * 8),
          (__attribute__((address_space(3))) void*)(&Bs[buf][c * 8]), 16, 0, 0);
    }
  };

  f32x4 acc[4][4] = {};
  stage(0, 0);
  stage(1, 1);
  int buf = 0;
  for (int t = 0; t < nkt; ++t) {
    if (t + 1 < nkt) asm volatile("s_waitcnt vmcnt(6)" ::: "memory");
    else             asm volatile("s_waitcnt vmcnt(0)" ::: "memory");
    __builtin_amdgcn_s_barrier();
    asm volatile("" ::: "memory");
    if (t + 2 < nkt) { int nb = buf + 2; if (nb >= 3) nb -= 3; stage(nb, t + 2); }
    const unsigned short* as = As[buf];
    const unsigned short* bs = Bs[buf];
#pragma unroll
    for (int h = 0; h < 2; ++h) {
      const int pos = ((h * 4 + quad) ^ sw) << 3;
      bf16x8 a[4], b[4];
#pragma unroll
      for (int tq = 0; tq < 4; ++tq) {
        a[tq] = *(const bf16x8*)(as + (wm + tq * 16 + lr) * 64 + pos);
        b[tq] = *(const bf16x8*)(bs + (wn + tq * 16 + lr) * 64 + pos);
      }
      __builtin_amdgcn_s_setprio(1);
#pragma unroll
      for (int mt = 0; mt < 4; ++mt)
#pragma unroll
        for (int nt = 0; nt < 4; ++nt)
          acc[mt][nt] = __builtin_amdgcn_mfma_f32_16x16x32_bf16(a[mt], b[nt], acc[mt][nt], 0, 0, 0);
      __builtin_amdgcn_s_setprio(0);
    }
    ++buf; if (buf >= 3) buf -= 3;
  }
  const int qd = quad << 2;
#pragma unroll
  for (int mt = 0; mt < 4; ++mt)
#pragma unroll
    for (int nt = 0; nt < 4; ++nt) {
      const int row = m0 + wm + mt * 16 + qd;
      const int col = n0 + wn + nt * 16 + lr;
#pragma unroll
      for (int r = 0; r < 4; ++r)
        C[(size_t)(row + r) * N + col] = acc[mt][nt][r];
    }
}

// ---------- GEMM1 + fused RoPE v2: same pipeline, 4M x 2N waves ----------
// Wave owns 32 rows x 128 cols = one full head (RoPE x1/x2 pairing stays intra-wave).
__global__ __launch_bounds__(512, 2) void gemm_rope_kernel(
    const unsigned short* __restrict__ A, const unsigned short* __restrict__ BT,
    const int* __restrict__ pos_ids, unsigned short* __restrict__ Qout) {
  __shared__ __align__(16) unsigned short As[3][128 * 64];
  __shared__ __align__(16) unsigned short Bs[3][256 * 64];
  const int tid = threadIdx.x;
  const int lane = tid & 63;
  const int wid = tid >> 6;               // 0..7
  const int wm = (wid >> 1) * 32;         // 4 M-waves x 32
  const int wn = (wid & 1) * 128;         // 2 N-waves x 128 (= one head)
  const int g = blockIdx.x;
  const int wg = (g & 7) * 32 + (g >> 3);
  const int m0 = (wg & 15) * 128;
  const int n0 = (wg >> 4) * 256;
  const int lr = lane & 15;
  const int quad = lane >> 4;
  const int sw = lr & 7;
  const int nkt = HID >> 6;

  auto stage = [&](int buf, int kt) {
#pragma unroll
    for (int p = 0; p < 2; ++p) {
      const int c = p * 512 + tid;
      const int r = c >> 3, j = (c & 7) ^ (r & 7);
      __builtin_amdgcn_global_load_lds(
          (const __attribute__((address_space(1))) void*)(A + (size_t)(m0 + r) * HID + kt * 64 + j * 8),
          (__attribute__((address_space(3))) void*)(&As[buf][c * 8]), 16, 0, 0);
    }
#pragma unroll
    for (int p = 0; p < 4; ++p) {
      const int c = p * 512 + tid;
      const int r = c >> 3, j = (c & 7) ^ (r & 7);
      __builtin_amdgcn_global_load_lds(
          (const __attribute__((address_space(1))) void*)(BT + (size_t)(n0 + r) * HID + kt * 64 + j * 8),
          (__attribute__((address_space(3))) void*)(&Bs[buf][c * 8]), 16, 0, 0);
    }
  };

  f32x4 acc[2][8] = {};
  stage(0, 0);
  stage(1, 1);
  int buf = 0;
  for (int t = 0; t < nkt; ++t) {
    if (t + 1 < nkt) asm volatile("s_waitcnt vmcnt(6)" ::: "memory");
    else             asm volatile("s_waitcnt vmcnt(0)" ::: "memory");
    __builtin_amdgcn_s_barrier();
    asm volatile("" ::: "memory");
    if (t + 2 < nkt) { int nb = buf + 2; if (nb >= 3) nb -= 3; stage(nb, t + 2); }
    const unsigned short* as = As[buf];
    const unsigned short* bs = Bs[buf];
#pragma unroll
    for (int h = 0; h < 2; ++h) {
      const int pos = ((h * 4 + quad) ^ sw) << 3;
      bf16x8 a[2], b[8];
#pragma unroll
      for (int tq = 0; tq < 2; ++tq)
        a[tq] = *(const bf16x8*)(as + (wm + tq * 16 + lr) * 64 + pos);
#pragma unroll
      for (int tq = 0; tq < 8; ++tq)
        b[tq] = *(const bf16x8*)(bs + (wn + tq * 16 + lr) * 64 + pos);
      __builtin_amdgcn_s_setprio(1);
#pragma unroll
      for (int mt = 0; mt < 2; ++mt)
#pragma unroll
        for (int nt = 0; nt < 8; ++nt)
          acc[mt][nt] = __builtin_amdgcn_mfma_f32_16x16x32_bf16(a[mt], b[nt], acc[mt][nt], 0, 0, 0);
      __builtin_amdgcn_s_setprio(0);
    }
    ++buf; if (buf >= 3) buf -= 3;
  }
  const int qd = quad << 2;
  const int h = (n0 + wn) >> 7;
#pragma unroll
  for (int mt = 0; mt < 2; ++mt)
#pragma unroll
    for (int r = 0; r < 4; ++r) {
      const int row = m0 + wm + mt * 16 + qd + r;
      const float pos = (float)pos_ids[row];
#pragma unroll
      for (int nt = 0; nt < 4; ++nt) {
        const int i = nt * 16 + lr;
        const float invf = __expf(-(float)(2 * i) * (9.2103403719761836f / 128.0f));
        float sn, cs;
        __sincosf(pos * invf, &sn, &cs);
        const float x1 = acc[mt][nt][r], x2 = acc[mt][nt + 4][r];
        Qout[((size_t)h * S_LEN + row) * HD + i]      = f2bf(x1 * cs - x2 * sn);
        Qout[((size_t)h * S_LEN + row) * HD + i + 64] = f2bf(x2 * cs + x1 * sn);
      }
    }
}

// ---------- flash attention v7: 4-wave, dbuf gload_lds K/V, in-register P ----------
__global__ __launch_bounds__(256, 2) void attn_kernel(
    const unsigned short* __restrict__ Q, const unsigned short* __restrict__ Kc,
    const unsigned short* __restrict__ VT, unsigned short* __restrict__ Aout) {
  __shared__ __align__(16) unsigned short Ks[2][64 * 128];   // [buf][skey][d], chunk-swizzled
  __shared__ __align__(16) unsigned short Vs[2][128 * 64];   // [buf][d][skey], chunk-swizzled
  const int tid = threadIdx.x, lane = tid & 63, wid = tid >> 6;
  const int qh = blockIdx.x;
  const int qt = (blockIdx.y < 8) ? (15 - (int)blockIdx.y) : ((int)blockIdx.y - 8);
  const int kvh = qh >> 2;
  const int lr = lane & 15, quad = lane >> 4;
  const float SC = 0.12751619754705767f;   // (1/sqrt(128)) * log2(e)
  const float NB = -23.083120654223414f;   // -16 * log2(e)

  bf16x8 qf[2][4];
#pragma unroll
  for (int mt = 0; mt < 2; ++mt)
#pragma unroll
    for (int kk = 0; kk < 4; ++kk)
      qf[mt][kk] = *(const bf16x8*)(Q + ((size_t)qh * S_LEN + qt * 128 + wid * 32 + mt * 16 + lr) * HD + kk * 32 + quad * 8);

  f32x4 o[2][8] = {};
  float lsum[2] = {0.f, 0.f};
  const int nkt = 2 * qt + 2;
  const int swz = lr & 7;

  auto stage = [&](int buf, int kt2) {
#pragma unroll
    for (int p = 0; p < 4; ++p) {
      const int c = p * 256 + tid;
      const int kr = c >> 4, kj = (c & 15) ^ (kr & 7);
      __builtin_amdgcn_global_load_lds(
          (const __attribute__((address_space(1))) void*)(Kc + ((size_t)kvh * S_LEN + kt2 * 64 + kr) * HD + kj * 8),
          (__attribute__((address_space(3))) void*)(&Ks[buf][c * 8]), 16, 0, 0);
      const int vr = c >> 3, vj = (c & 7) ^ (vr & 7);
      __builtin_amdgcn_global_load_lds(
          (const __attribute__((address_space(1))) void*)(VT + ((size_t)kvh * HD + vr) * S_LEN + kt2 * 64 + vj * 8),
          (__attribute__((address_space(3))) void*)(&Vs[buf][c * 8]), 16, 0, 0);
    }
  };

  stage(0, 0);
  __syncthreads();

  for (int kt2 = 0; kt2 < nkt; ++kt2) {
    const int cur = kt2 & 1;
    if (kt2 + 1 < nkt) stage(cur ^ 1, kt2 + 1);
    const unsigned short* KsC = Ks[cur];
    const unsigned short* VsC = Vs[cur];
    const bool dtile = (kt2 >= 2 * qt);

    uint32_t Pw[2][4][2];
#pragma unroll
    for (int nt = 0; nt < 4; ++nt) {
      f32x4 s0 = {}, s1 = {};
      __builtin_amdgcn_s_setprio(1);
#pragma unroll
      for (int kk = 0; kk < 4; ++kk) {
        bf16x8 kf = *(const bf16x8*)(KsC + (nt * 16 + lr) * 128 + (((kk * 4 + quad) ^ swz) * 8));
        s0 = __builtin_amdgcn_mfma_f32_16x16x32_bf16(kf, qf[0][kk], s0, 0, 0, 0);
        s1 = __builtin_amdgcn_mfma_f32_16x16x32_bf16(kf, qf[1][kk], s1, 0, 0, 0);
      }
      __builtin_amdgcn_s_setprio(0);
      const int skey0 = kt2 * 64 + nt * 16 + quad * 4;
#pragma unroll
      for (int mt = 0; mt < 2; ++mt) {
        const f32x4 s = mt ? s1 : s0;
        const int qrow = qt * 128 + wid * 32 + mt * 16 + lr;
        float pv[4];
        float ls = 0.f;
#pragma unroll
        for (int r = 0; r < 4; ++r) {
          float v = fmaf(s[r], SC, NB);
          if (dtile && (skey0 + r) > qrow) v = -1e30f;
          pv[r] = exp2_fast(v);
          ls += pv[r];
        }
        lsum[mt] += ls;
        Pw[mt][nt][0] = cvt_pk_bf16(pv[0], pv[1]);
        Pw[mt][nt][1] = cvt_pk_bf16(pv[2], pv[3]);
      }
    }

    bf16x8 pf[2][2];
#pragma unroll
    for (int mt = 0; mt < 2; ++mt)
#pragma unroll
      for (int k = 0; k < 2; ++k) {
        uint32_t w4[4];
#pragma unroll
        for (int w = 0; w < 2; ++w) {
          uint32_t x = Pw[mt][2 * k][w], y = Pw[mt][2 * k + 1][w];
          asm("v_permlane32_swap_b32 %0, %1" : "+v"(x), "+v"(y));
          uint32_t xe = x, xo = x;
          asm("v_permlane16_swap_b32 %0, %1" : "+v"(xe), "+v"(xo));
          uint32_t ye = y, yo = y;
          asm("v_permlane16_swap_b32 %0, %1" : "+v"(ye), "+v"(yo));
          const bool qodd = (quad & 1) != 0;
          w4[0 + w] = qodd ? ye : xe;
          w4[2 + w] = qodd ? yo : xo;
        }
        union { uint32_t u[4]; bf16x8 v; } P;
        P.u[0] = w4[0]; P.u[1] = w4[1]; P.u[2] = w4[2]; P.u[3] = w4[3];
        pf[mt][k] = P.v;
      }

    __builtin_amdgcn_s_setprio(1);
#pragma unroll
    for (int dt = 0; dt < 8; ++dt)
#pragma unroll
      for (int kk = 0; kk < 2; ++kk) {
        bf16x8 vf = *(const bf16x8*)(VsC + (dt * 16 + lr) * 64 + (((kk * 4 + quad) ^ swz) * 8));
        o[0][dt] = __builtin_amdgcn_mfma_f32_16x16x32_bf16(vf, pf[0][kk], o[0][dt], 0, 0, 0);
        o[1][dt] = __builtin_amdgcn_mfma_f32_16x16x32_bf16(vf, pf[1][kk], o[1][dt], 0, 0, 0);
      }
    __builtin_amdgcn_s_setprio(0);

    __syncthreads();
  }

#pragma unroll
  for (int mt = 0; mt < 2; ++mt) {
    float l = lsum[mt];
    l += __shfl_xor(l, 16);
    l += __shfl_xor(l, 32);
    const float inv = 1.0f / l;
    const int qrow = qt * 128 + wid * 32 + mt * 16 + lr;
#pragma unroll
    for (int dt = 0; dt < 8; ++dt) {
      uint2 w;
      w.x = cvt_pk_bf16(o[mt][dt][0] * inv, o[mt][dt][1] * inv);
      w.y = cvt_pk_bf16(o[mt][dt][2] * inv, o[mt][dt][3] * inv);
      *(uint2*)(Aout + (size_t)qrow * HID + qh * HD + dt * 16 + quad * 4) = w;
    }
  }
}

extern "C" void kernel_launch(void* const* d_in, const int* in_sizes, int n_in,
                              void* d_out, int out_size, void* d_ws, size_t ws_size,
                              hipStream_t stream) {
  const float* hidden  = (const float*)d_in[0];   // [1][2048][4096]
  const float* k_cache = (const float*)d_in[1];   // [1][8][2048][128]
  const float* v_cache = (const float*)d_in[2];   // [1][8][2048][128]
  const float* Wq      = (const float*)d_in[3];   // [4096][4096]
  const float* Wo      = (const float*)d_in[4];   // [4096][4096]
  const int*   pos     = (const int*)d_in[5];     // [1][2048]
  float* out = (float*)d_out;

  char* ws = (char*)d_ws;
  unsigned short* hidden_bf = (unsigned short*)(ws + 0);            // 16 MB
  unsigned short* attn_bf   = hidden_bf;                            // alias (hidden dead after GEMM1)
  unsigned short* WqT       = (unsigned short*)(ws + 16777216);     // 32 MB
  unsigned short* WoT       = (unsigned short*)(ws + 50331648);     // 32 MB
  unsigned short* k_bf      = (unsigned short*)(ws + 83886080);     // 4 MB
  unsigned short* vT        = (unsigned short*)(ws + 88080384);     // 4 MB
  unsigned short* q_bf      = (unsigned short*)(ws + 92274688);     // 16 MB

  cvt_bf16_kernel<<<(S_LEN * HID / 4 + 255) / 256, 256, 0, stream>>>(hidden, hidden_bf, S_LEN * HID / 4);
  cvt_bf16_kernel<<<(NKV * S_LEN * HD / 4 + 255) / 256, 256, 0, stream>>>(k_cache, k_bf, NKV * S_LEN * HD / 4);
  transpose_cvt2_kernel<<<dim3(HID / 64, HID / 64, 2), 256, 0, stream>>>(Wq, WqT, Wo, WoT, HID, HID);
  transpose_cvt_kernel<<<dim3(HD / 64, S_LEN / 64, NKV), 256, 0, stream>>>(v_cache, vT, S_LEN, HD);

  gemm_rope_kernel<<<dim3((S_LEN / 128) * (HID / 256)), 512, 0, stream>>>(hidden_bf, WqT, pos, q_bf);
  attn_kernel<<<dim3(NH, S_LEN / 128), 256, 0, stream>>>(q_bf, k_bf, vT, attn_bf);
  gemm_bt_kernel<<<dim3((S_LEN / 128) * (HID / 256)), 512, 0, stream>>>(attn_bf, WoT, out, S_LEN, HID, HID);
}

// Round 4
// 421.970 us; speedup vs baseline: 1.1014x; 1.1014x over previous
//
#include <hip/hip_runtime.h>
#include <cstdint>
#include <cstddef>

// ---------- constants for this problem ----------
#define S_LEN 2048
#define HID 4096
#define NH 32
#define NKV 8
#define HD 128

typedef __attribute__((ext_vector_type(4))) float f32x4;
typedef __attribute__((ext_vector_type(8))) short bf16x8;

__device__ __forceinline__ unsigned short f2bf(float f) {
  union { float f; uint32_t u; } v; v.f = f;
  uint32_t r = v.u + 0x7FFFu + ((v.u >> 16) & 1u);  // round-to-nearest-even
  return (unsigned short)(r >> 16);
}

__device__ __forceinline__ float exp2_fast(float x) {
#if __has_builtin(__builtin_amdgcn_exp2f)
  return __builtin_amdgcn_exp2f(x);
#else
  float r; asm("v_exp_f32 %0, %1" : "=v"(r) : "v"(x)); return r;
#endif
}

// pack two f32 -> one u32 of 2x bf16 (RNE) via hw instruction (T12 recipe)
__device__ __forceinline__ unsigned int cvt_pk_bf16(float lo, float hi) {
  unsigned int r;
  asm("v_cvt_pk_bf16_f32 %0, %1, %2" : "=v"(r) : "v"(lo), "v"(hi));
  return r;
}

// ---------- fp32 -> bf16 straight cast (vectorized x4) ----------
__global__ void cvt_bf16_kernel(const float* __restrict__ in,
                                unsigned short* __restrict__ out, int n4) {
  int i = blockIdx.x * blockDim.x + threadIdx.x;
  if (i >= n4) return;
  float4 v = ((const float4*)in)[i];
  ushort4 o;
  o.x = f2bf(v.x); o.y = f2bf(v.y); o.z = f2bf(v.z); o.w = f2bf(v.w);
  ((ushort4*)out)[i] = o;
}

// ---------- fp32 [b][R][C] -> bf16 [b][C][R] transpose-cast, 64x64 tiles ----------
__global__ __launch_bounds__(256) void transpose_cvt2_kernel(
    const float* __restrict__ in0, unsigned short* __restrict__ out0,
    const float* __restrict__ in1, unsigned short* __restrict__ out1,
    int R, int C) {
  __shared__ float tile[64][65];
  const float* inb = (blockIdx.z == 0) ? in0 : in1;
  unsigned short* outb = (blockIdx.z == 0) ? out0 : out1;
  const int c0 = blockIdx.x * 64, r0 = blockIdx.y * 64;
  const int tid = threadIdx.x;
#pragma unroll
  for (int p = 0; p < 4; ++p) {
    const int ch = p * 256 + tid;
    const int r = ch >> 4, off = (ch & 15) << 2;
    *(float4*)&tile[r][off] = *(const float4*)(inb + (size_t)(r0 + r) * C + c0 + off);
  }
  __syncthreads();
#pragma unroll
  for (int p = 0; p < 2; ++p) {
    const int ch = p * 256 + tid;
    const int i = ch >> 3, j0 = (ch & 7) << 3;
    bf16x8 v;
#pragma unroll
    for (int k = 0; k < 8; ++k) v[k] = (short)f2bf(tile[j0 + k][i]);
    *(bf16x8*)(outb + (size_t)(c0 + i) * R + r0 + j0) = v;
  }
}

// per-batch variant for v_cache [NKV][S][HD] -> [NKV][HD][S]
__global__ __launch_bounds__(256) void transpose_cvt_kernel(
    const float* __restrict__ in, unsigned short* __restrict__ out, int R, int C) {
  __shared__ float tile[64][65];
  const int b = blockIdx.z;
  const float* inb = in + (size_t)b * R * C;
  unsigned short* outb = out + (size_t)b * R * C;
  const int c0 = blockIdx.x * 64, r0 = blockIdx.y * 64;
  const int tid = threadIdx.x;
#pragma unroll
  for (int p = 0; p < 4; ++p) {
    const int ch = p * 256 + tid;
    const int r = ch >> 4, off = (ch & 15) << 2;
    *(float4*)&tile[r][off] = *(const float4*)(inb + (size_t)(r0 + r) * C + c0 + off);
  }
  __syncthreads();
#pragma unroll
  for (int p = 0; p < 2; ++p) {
    const int ch = p * 256 + tid;
    const int i = ch >> 3, j0 = (ch & 7) << 3;
    bf16x8 v;
#pragma unroll
    for (int k = 0; k < 8; ++k) v[k] = (short)f2bf(tile[j0 + k][i]);
    *(bf16x8*)(outb + (size_t)(c0 + i) * R + r0 + j0) = v;
  }
}

// ---------- bf16 GEMM, BK=64, XOR-swizzled LDS, T3-minimum dbuf ----------
// Round-0 geometry (128x128, 4 waves, 2 blocks/CU) with the guide's minimum
// 2-phase pipeline: double-buffered LDS, stage(t+1) issued BEFORE compute(t),
// ONE __syncthreads per K-tile (its implicit vmcnt(0)+lgkmcnt(0) drain is the
// required fence). Stage latency hides under the wave's own ds_read+MFMA phase.
// Race: barrier at end of t proves all waves finished reading buf AND staging
// buf^1 -> iter t+1 reads buf^1 / overwrites buf safely.
__global__ __launch_bounds__(256, 2) void gemm_bt_kernel(
    const unsigned short* __restrict__ A, const unsigned short* __restrict__ BT,
    float* __restrict__ C, int M, int N, int K) {
  __shared__ __align__(16) unsigned short As[2][128 * 64];
  __shared__ __align__(16) unsigned short Bs[2][128 * 64];
  const int tid = threadIdx.x;
  const int lane = tid & 63;
  const int wid = tid >> 6;
  const int wm = (wid >> 1) * 64, wn = (wid & 1) * 64;
  const int g = blockIdx.x;
  const int xcd = g & 7, local = g >> 3;
  const int m0 = (xcd * 2 + (local & 1)) * 128;
  const int n0 = (local >> 1) * 128;
  const int lr = lane & 15;
  const int quad = lane >> 4;
  const int sw = lr & 7;
  const int nkt = K >> 6;

  auto stage = [&](int buf, int kt) {
#pragma unroll
    for (int p = 0; p < 4; ++p) {
      const int c = p * 256 + tid;
      const int r = c >> 3, jsrc = (c & 7) ^ (r & 7);
      __builtin_amdgcn_global_load_lds(
          (const __attribute__((address_space(1))) void*)(A + (size_t)(m0 + r) * K + kt * 64 + jsrc * 8),
          (__attribute__((address_space(3))) void*)(&As[buf][c * 8]), 16, 0, 0);
      __builtin_amdgcn_global_load_lds(
          (const __attribute__((address_space(1))) void*)(BT + (size_t)(n0 + r) * K + kt * 64 + jsrc * 8),
          (__attribute__((address_space(3))) void*)(&Bs[buf][c * 8]), 16, 0, 0);
    }
  };

  f32x4 acc[4][4] = {};
  stage(0, 0);
  __syncthreads();
  int bufv = 0;
  for (int t = 0; t < nkt; ++t) {
    if (t + 1 < nkt) stage(bufv ^ 1, t + 1);   // issue-only; drains at the barrier
    const unsigned short* as = As[bufv];
    const unsigned short* bs = Bs[bufv];
#pragma unroll
    for (int h = 0; h < 2; ++h) {
      const int pos = ((h * 4 + quad) ^ sw) << 3;
      bf16x8 a[4], b[4];
#pragma unroll
      for (int tq = 0; tq < 4; ++tq) {
        a[tq] = *(const bf16x8*)(as + (wm + tq * 16 + lr) * 64 + pos);
        b[tq] = *(const bf16x8*)(bs + (wn + tq * 16 + lr) * 64 + pos);
      }
#pragma unroll
      for (int mt = 0; mt < 4; ++mt)
#pragma unroll
        for (int nt = 0; nt < 4; ++nt)
          acc[mt][nt] = __builtin_amdgcn_mfma_f32_16x16x32_bf16(a[mt], b[nt], acc[mt][nt], 0, 0, 0);
    }
    __syncthreads();
    bufv ^= 1;
  }
  const int qd = quad << 2;
#pragma unroll
  for (int mt = 0; mt < 4; ++mt)
#pragma unroll
    for (int nt = 0; nt < 4; ++nt) {
      const int row = m0 + wm + mt * 16 + qd;
      const int col = n0 + wn + nt * 16 + lr;
#pragma unroll
      for (int r = 0; r < 4; ++r)
        C[(size_t)(row + r) * N + col] = acc[mt][nt][r];
    }
}

// ---------- GEMM1 + fused RoPE, BK=64, XOR-swizzled LDS, T3-minimum dbuf ----------
__global__ __launch_bounds__(256, 2) void gemm_rope_kernel(
    const unsigned short* __restrict__ A, const unsigned short* __restrict__ BT,
    const int* __restrict__ pos_ids, unsigned short* __restrict__ Qout) {
  __shared__ __align__(16) unsigned short As[2][128 * 64];
  __shared__ __align__(16) unsigned short Bs[2][128 * 64];
  const int tid = threadIdx.x;
  const int lane = tid & 63;
  const int wid = tid >> 6;
  const int wm = wid * 32;
  const int g = blockIdx.x;
  const int xcd = g & 7, local = g >> 3;
  const int m0 = (xcd * 2 + (local & 1)) * 128;
  const int n0 = (local >> 1) * 128;
  const int lr = lane & 15;
  const int quad = lane >> 4;
  const int sw = lr & 7;
  const int nkt = HID >> 6;

  auto stage = [&](int buf, int kt) {
#pragma unroll
    for (int p = 0; p < 4; ++p) {
      const int c = p * 256 + tid;
      const int r = c >> 3, jsrc = (c & 7) ^ (r & 7);
      __builtin_amdgcn_global_load_lds(
          (const __attribute__((address_space(1))) void*)(A + (size_t)(m0 + r) * HID + kt * 64 + jsrc * 8),
          (__attribute__((address_space(3))) void*)(&As[buf][c * 8]), 16, 0, 0);
      __builtin_amdgcn_global_load_lds(
          (const __attribute__((address_space(1))) void*)(BT + (size_t)(n0 + r) * HID + kt * 64 + jsrc * 8),
          (__attribute__((address_space(3))) void*)(&Bs[buf][c * 8]), 16, 0, 0);
    }
  };

  f32x4 acc[2][8] = {};
  stage(0, 0);
  __syncthreads();
  int bufv = 0;
  for (int t = 0; t < nkt; ++t) {
    if (t + 1 < nkt) stage(bufv ^ 1, t + 1);
    const unsigned short* as = As[bufv];
    const unsigned short* bs = Bs[bufv];
#pragma unroll
    for (int h = 0; h < 2; ++h) {
      const int pos = ((h * 4 + quad) ^ sw) << 3;
      bf16x8 a[2], b[8];
#pragma unroll
      for (int tq = 0; tq < 2; ++tq)
        a[tq] = *(const bf16x8*)(as + (wm + tq * 16 + lr) * 64 + pos);
#pragma unroll
      for (int tq = 0; tq < 8; ++tq)
        b[tq] = *(const bf16x8*)(bs + (tq * 16 + lr) * 64 + pos);
#pragma unroll
      for (int mt = 0; mt < 2; ++mt)
#pragma unroll
        for (int nt = 0; nt < 8; ++nt)
          acc[mt][nt] = __builtin_amdgcn_mfma_f32_16x16x32_bf16(a[mt], b[nt], acc[mt][nt], 0, 0, 0);
    }
    __syncthreads();
    bufv ^= 1;
  }
  const int qd = quad << 2;
  const int h = n0 >> 7;
#pragma unroll
  for (int mt = 0; mt < 2; ++mt)
#pragma unroll
    for (int r = 0; r < 4; ++r) {
      const int row = m0 + wm + mt * 16 + qd + r;
      const float pos = (float)pos_ids[row];
#pragma unroll
      for (int nt = 0; nt < 4; ++nt) {
        const int i = nt * 16 + lr;
        const float invf = __expf(-(float)(2 * i) * (9.2103403719761836f / 128.0f));
        float sn, cs;
        __sincosf(pos * invf, &sn, &cs);
        const float x1 = acc[mt][nt][r], x2 = acc[mt][nt + 4][r];
        Qout[((size_t)h * S_LEN + row) * HD + i]      = f2bf(x1 * cs - x2 * sn);
        Qout[((size_t)h * S_LEN + row) * HD + i + 64] = f2bf(x2 * cs + x1 * sn);
      }
    }
}

// ---------- flash attention v5 (proven 78.8us structure) + VALU slimming ----------
// Structure byte-identical to round-0: transposed-S form, 4 waves x 32 qrows,
// reg-staged K/V, Ks/Vs/Ps LDS regions, 2 barriers/tile. Only change: softmax
// exp via exp2(fma) (bit-equiv to __expf(s*scale-16)) and P/O bf16 packing via
// v_cvt_pk_bf16_f32 (2 insts per 4 values vs ~16 int ops).
__global__ __launch_bounds__(256, 2) void attn_kernel(
    const unsigned short* __restrict__ Q, const unsigned short* __restrict__ Kc,
    const unsigned short* __restrict__ VT, unsigned short* __restrict__ Aout) {
  __shared__ __align__(16) unsigned short Ks[64 * 136];   // [skey][d]
  __shared__ __align__(16) unsigned short Vs[128 * 72];   // [d][skey]
  __shared__ __align__(16) unsigned short Ps[128 * 72];   // [qrow][skey]
  const int tid = threadIdx.x, lane = tid & 63, wid = tid >> 6;
  const int qh = blockIdx.x;
  const int qt = (blockIdx.y < 8) ? (15 - (int)blockIdx.y) : ((int)blockIdx.y - 8);
  const int kvh = qh >> 2;
  const int lr = lane & 15, quad = lane >> 4;
  const float SC = 0.12751619754705767f;   // (1/sqrt(128)) * log2(e)
  const float NB = -23.083120654223414f;   // -16 * log2(e)

  // Q fragments (B-operand: n=qrow=lane&15, k=d=quad*8+j)
  bf16x8 qf[2][4];
#pragma unroll
  for (int mt = 0; mt < 2; ++mt)
#pragma unroll
    for (int kk = 0; kk < 4; ++kk)
      qf[mt][kk] = *(const bf16x8*)(Q + ((size_t)qh * S_LEN + qt * 128 + wid * 32 + mt * 16 + lr) * HD + kk * 32 + quad * 8);

  f32x4 o[2][8] = {};        // O^T acc: row=d (quad*4+r within dt), col=qrow(lr)
  float lsum[2] = {0.f, 0.f};

  const int prow0 = (wid * 32 + lr) * 72;  // base for this lane's P rows (mt adds 16*72)
  const int nkt = 2 * qt + 2;
  for (int kt2 = 0; kt2 < nkt; ++kt2) {
    // global loads first (overlap previous iteration's compute)
    bf16x8 kr[4], vr[4];
#pragma unroll
    for (int p = 0; p < 4; ++p) {
      const int c = p * 256 + tid;
      kr[p] = *(const bf16x8*)(Kc + ((size_t)kvh * S_LEN + kt2 * 64 + (c >> 4)) * HD + (c & 15) * 8);
      vr[p] = *(const bf16x8*)(VT + ((size_t)kvh * HD + (c >> 3)) * S_LEN + kt2 * 64 + (c & 7) * 8);
    }
    __syncthreads();  // B1: all waves done reading Ks/Vs from prev iter
#pragma unroll
    for (int p = 0; p < 4; ++p) {
      const int c = p * 256 + tid;
      *(bf16x8*)(Ks + (c >> 4) * 136 + (c & 15) * 8) = kr[p];
      *(bf16x8*)(Vs + (c >> 3) * 72 + (c & 7) * 8) = vr[p];
    }
    __syncthreads();  // B2: tiles staged

    const bool dtile = (kt2 >= 2 * qt);  // last two 64-key tiles intersect the diagonal
    // QK^T (transposed) + fused fixed-max softmax + packed P write
#pragma unroll
    for (int nt = 0; nt < 4; ++nt) {
      f32x4 s0 = {}, s1 = {};
#pragma unroll
      for (int kk = 0; kk < 4; ++kk) {
        bf16x8 kf = *(const bf16x8*)(Ks + (nt * 16 + lr) * 136 + kk * 32 + quad * 8);
        s0 = __builtin_amdgcn_mfma_f32_16x16x32_bf16(kf, qf[0][kk], s0, 0, 0, 0);
        s1 = __builtin_amdgcn_mfma_f32_16x16x32_bf16(kf, qf[1][kk], s1, 0, 0, 0);
      }
      const int skey0 = kt2 * 64 + nt * 16 + quad * 4;  // this lane's 4 consecutive keys
#pragma unroll
      for (int mt = 0; mt < 2; ++mt) {
        const f32x4 s = mt ? s1 : s0;
        const int qrow = qt * 128 + wid * 32 + mt * 16 + lr;
        float pv[4];
        float ls = 0.f;
#pragma unroll
        for (int r = 0; r < 4; ++r) {
          float v = fmaf(s[r], SC, NB);
          if (dtile && (skey0 + r) > qrow) v = -1e30f;
          pv[r] = exp2_fast(v);
          ls += pv[r];
        }
        lsum[mt] += ls;
        uint2 pk;
        pk.x = cvt_pk_bf16(pv[0], pv[1]);
        pk.y = cvt_pk_bf16(pv[2], pv[3]);
        *(uint2*)(Ps + prow0 + mt * 16 * 72 + nt * 16 + quad * 4) = pk;  // b64, 2-way banks
      }
    }
    // PV: O^T += V^T · P^T  (wave-local P rows; in-wave LDS ordering, no barrier)
    bf16x8 pf[2][2];
#pragma unroll
    for (int mt = 0; mt < 2; ++mt)
#pragma unroll
      for (int kk = 0; kk < 2; ++kk)
        pf[mt][kk] = *(const bf16x8*)(Ps + prow0 + mt * 16 * 72 + kk * 32 + quad * 8);
#pragma unroll
    for (int dt = 0; dt < 8; ++dt)
#pragma unroll
      for (int kk = 0; kk < 2; ++kk) {
        bf16x8 vf = *(const bf16x8*)(Vs + (dt * 16 + lr) * 72 + kk * 32 + quad * 8);
        o[0][dt] = __builtin_amdgcn_mfma_f32_16x16x32_bf16(vf, pf[0][kk], o[0][dt], 0, 0, 0);
        o[1][dt] = __builtin_amdgcn_mfma_f32_16x16x32_bf16(vf, pf[1][kk], o[1][dt], 0, 0, 0);
      }
  }

  // epilogue: reduce lsum over the 4 lanes sharing each qrow (quad axis), scale, store
#pragma unroll
  for (int mt = 0; mt < 2; ++mt) {
    float l = lsum[mt];
    l += __shfl_xor(l, 16);
    l += __shfl_xor(l, 32);
    const float inv = 1.0f / l;
    const int qrow = qt * 128 + wid * 32 + mt * 16 + lr;
#pragma unroll
    for (int dt = 0; dt < 8; ++dt) {
      uint2 w;
      w.x = cvt_pk_bf16(o[mt][dt][0] * inv, o[mt][dt][1] * inv);
      w.y = cvt_pk_bf16(o[mt][dt][2] * inv, o[mt][dt][3] * inv);
      *(uint2*)(Aout + (size_t)qrow * HID + qh * HD + dt * 16 + quad * 4) = w;
    }
  }
}

extern "C" void kernel_launch(void* const* d_in, const int* in_sizes, int n_in,
                              void* d_out, int out_size, void* d_ws, size_t ws_size,
                              hipStream_t stream) {
  const float* hidden  = (const float*)d_in[0];   // [1][2048][4096]
  const float* k_cache = (const float*)d_in[1];   // [1][8][2048][128]
  const float* v_cache = (const float*)d_in[2];   // [1][8][2048][128]
  const float* Wq      = (const float*)d_in[3];   // [4096][4096]
  const float* Wo      = (const float*)d_in[4];   // [4096][4096]
  const int*   pos     = (const int*)d_in[5];     // [1][2048]
  float* out = (float*)d_out;

  char* ws = (char*)d_ws;
  unsigned short* hidden_bf = (unsigned short*)(ws + 0);            // 16 MB
  unsigned short* attn_bf   = hidden_bf;                            // alias (hidden dead after GEMM1)
  unsigned short* WqT       = (unsigned short*)(ws + 16777216);     // 32 MB
  unsigned short* WoT       = (unsigned short*)(ws + 50331648);     // 32 MB
  unsigned short* k_bf      = (unsigned short*)(ws + 83886080);     // 4 MB
  unsigned short* vT        = (unsigned short*)(ws + 88080384);     // 4 MB
  unsigned short* q_bf      = (unsigned short*)(ws + 92274688);     // 16 MB

  cvt_bf16_kernel<<<(S_LEN * HID / 4 + 255) / 256, 256, 0, stream>>>(hidden, hidden_bf, S_LEN * HID / 4);
  cvt_bf16_kernel<<<(NKV * S_LEN * HD / 4 + 255) / 256, 256, 0, stream>>>(k_cache, k_bf, NKV * S_LEN * HD / 4);
  transpose_cvt2_kernel<<<dim3(HID / 64, HID / 64, 2), 256, 0, stream>>>(Wq, WqT, Wo, WoT, HID, HID);
  transpose_cvt_kernel<<<dim3(HD / 64, S_LEN / 64, NKV), 256, 0, stream>>>(v_cache, vT, S_LEN, HD);

  gemm_rope_kernel<<<dim3((S_LEN / 128) * (HID / 128)), 256, 0, stream>>>(hidden_bf, WqT, pos, q_bf);
  attn_kernel<<<dim3(NH, S_LEN / 128), 256, 0, stream>>>(q_bf, k_bf, vT, attn_bf);
  gemm_bt_kernel<<<dim3((S_LEN / 128) * (HID / 128)), 256, 0, stream>>>(attn_bf, WoT, out, S_LEN, HID, HID);
}

// Round 5
// 412.805 us; speedup vs baseline: 1.1258x; 1.0222x over previous
//
#include <hip/hip_runtime.h>
#include <cstdint>
#include <cstddef>

// ---------- constants for this problem ----------
#define S_LEN 2048
#define HID 4096
#define NH 32
#define NKV 8
#define HD 128

typedef __attribute__((ext_vector_type(4))) float f32x4;
typedef __attribute__((ext_vector_type(8))) short bf16x8;

__device__ __forceinline__ unsigned short f2bf(float f) {
  union { float f; uint32_t u; } v; v.f = f;
  uint32_t r = v.u + 0x7FFFu + ((v.u >> 16) & 1u);  // round-to-nearest-even
  return (unsigned short)(r >> 16);
}

__device__ __forceinline__ float exp2_fast(float x) {
#if __has_builtin(__builtin_amdgcn_exp2f)
  return __builtin_amdgcn_exp2f(x);
#else
  float r; asm("v_exp_f32 %0, %1" : "=v"(r) : "v"(x)); return r;
#endif
}

// pack two f32 -> one u32 of 2x bf16 (RNE) via hw instruction (T12 recipe)
__device__ __forceinline__ unsigned int cvt_pk_bf16(float lo, float hi) {
  unsigned int r;
  asm("v_cvt_pk_bf16_f32 %0, %1, %2" : "=v"(r) : "v"(lo), "v"(hi));
  return r;
}

// ---------- fused fp32 -> bf16 casts: hidden + k_cache in one launch ----------
// Pure index split, no LDS, both paths byte-identical code (avoids the round-1
// mixed-LDS-occupancy confound). 2097152 + 524288 = 2621440 float4s = 10240 blocks.
__global__ void cvt2_bf16_kernel(const float* __restrict__ hidden,
                                 unsigned short* __restrict__ hidden_bf,
                                 const float* __restrict__ k_cache,
                                 unsigned short* __restrict__ k_bf) {
  const int i = blockIdx.x * blockDim.x + threadIdx.x;
  const float* in;
  unsigned short* out;
  int j;
  if (i < 2097152) { in = hidden; out = hidden_bf; j = i; }
  else             { in = k_cache; out = k_bf; j = i - 2097152; }
  float4 v = ((const float4*)in)[j];
  ushort4 o;
  o.x = f2bf(v.x); o.y = f2bf(v.y); o.z = f2bf(v.z); o.w = f2bf(v.w);
  ((ushort4*)out)[j] = o;
}

// ---------- fused transpose-cast: Wq (z=0), Wo (z=1), v_cache (z=2) ----------
// All paths use the identical 64x64 fp32 tile; z=2 remaps (x,y) onto the
// [NKV][2048][128] v transpose and early-exits the 3584 spare blocks.
__global__ __launch_bounds__(256) void transpose_cvt3_kernel(
    const float* __restrict__ Wq, unsigned short* __restrict__ WqT,
    const float* __restrict__ Wo, unsigned short* __restrict__ WoT,
    const float* __restrict__ v_cache, unsigned short* __restrict__ vT) {
  __shared__ float tile[64][65];
  const float* inb;
  unsigned short* outb;
  int R, C, c0, r0;
  if (blockIdx.z < 2) {
    inb = blockIdx.z ? Wo : Wq;
    outb = blockIdx.z ? WoT : WqT;
    R = HID; C = HID;
    c0 = blockIdx.x * 64; r0 = blockIdx.y * 64;
  } else {
    const int id = blockIdx.y * 64 + blockIdx.x;
    if (id >= 512) return;                 // NKV * (2048/64) * (128/64) = 512 tiles
    const int hd = id >> 6, rem = id & 63;
    inb = v_cache + (size_t)hd * S_LEN * HD;
    outb = vT + (size_t)hd * S_LEN * HD;
    R = S_LEN; C = HD;
    c0 = (rem & 1) * 64; r0 = (rem >> 1) * 64;
  }
  const int tid = threadIdx.x;
#pragma unroll
  for (int p = 0; p < 4; ++p) {
    const int ch = p * 256 + tid;
    const int r = ch >> 4, off = (ch & 15) << 2;
    *(float4*)&tile[r][off] = *(const float4*)(inb + (size_t)(r0 + r) * C + c0 + off);
  }
  __syncthreads();
#pragma unroll
  for (int p = 0; p < 2; ++p) {
    const int ch = p * 256 + tid;
    const int i = ch >> 3, j0 = (ch & 7) << 3;
    bf16x8 v;
#pragma unroll
    for (int k = 0; k < 8; ++k) v[k] = (short)f2bf(tile[j0 + k][i]);
    *(bf16x8*)(outb + (size_t)(c0 + i) * R + r0 + j0) = v;
  }
}

// ---------- bf16 GEMM, BK=64, XOR-swizzled LDS, T3-minimum dbuf ----------
// (unchanged from round 4: 81.5us class, 0 bank conflicts)
__global__ __launch_bounds__(256, 2) void gemm_bt_kernel(
    const unsigned short* __restrict__ A, const unsigned short* __restrict__ BT,
    float* __restrict__ C, int M, int N, int K) {
  __shared__ __align__(16) unsigned short As[2][128 * 64];
  __shared__ __align__(16) unsigned short Bs[2][128 * 64];
  const int tid = threadIdx.x;
  const int lane = tid & 63;
  const int wid = tid >> 6;
  const int wm = (wid >> 1) * 64, wn = (wid & 1) * 64;
  const int g = blockIdx.x;
  const int xcd = g & 7, local = g >> 3;
  const int m0 = (xcd * 2 + (local & 1)) * 128;
  const int n0 = (local >> 1) * 128;
  const int lr = lane & 15;
  const int quad = lane >> 4;
  const int sw = lr & 7;
  const int nkt = K >> 6;

  auto stage = [&](int buf, int kt) {
#pragma unroll
    for (int p = 0; p < 4; ++p) {
      const int c = p * 256 + tid;
      const int r = c >> 3, jsrc = (c & 7) ^ (r & 7);
      __builtin_amdgcn_global_load_lds(
          (const __attribute__((address_space(1))) void*)(A + (size_t)(m0 + r) * K + kt * 64 + jsrc * 8),
          (__attribute__((address_space(3))) void*)(&As[buf][c * 8]), 16, 0, 0);
      __builtin_amdgcn_global_load_lds(
          (const __attribute__((address_space(1))) void*)(BT + (size_t)(n0 + r) * K + kt * 64 + jsrc * 8),
          (__attribute__((address_space(3))) void*)(&Bs[buf][c * 8]), 16, 0, 0);
    }
  };

  f32x4 acc[4][4] = {};
  stage(0, 0);
  __syncthreads();
  int bufv = 0;
  for (int t = 0; t < nkt; ++t) {
    if (t + 1 < nkt) stage(bufv ^ 1, t + 1);   // issue-only; drains at the barrier
    const unsigned short* as = As[bufv];
    const unsigned short* bs = Bs[bufv];
#pragma unroll
    for (int h = 0; h < 2; ++h) {
      const int pos = ((h * 4 + quad) ^ sw) << 3;
      bf16x8 a[4], b[4];
#pragma unroll
      for (int tq = 0; tq < 4; ++tq) {
        a[tq] = *(const bf16x8*)(as + (wm + tq * 16 + lr) * 64 + pos);
        b[tq] = *(const bf16x8*)(bs + (wn + tq * 16 + lr) * 64 + pos);
      }
#pragma unroll
      for (int mt = 0; mt < 4; ++mt)
#pragma unroll
        for (int nt = 0; nt < 4; ++nt)
          acc[mt][nt] = __builtin_amdgcn_mfma_f32_16x16x32_bf16(a[mt], b[nt], acc[mt][nt], 0, 0, 0);
    }
    __syncthreads();
    bufv ^= 1;
  }
  const int qd = quad << 2;
#pragma unroll
  for (int mt = 0; mt < 4; ++mt)
#pragma unroll
    for (int nt = 0; nt < 4; ++nt) {
      const int row = m0 + wm + mt * 16 + qd;
      const int col = n0 + wn + nt * 16 + lr;
#pragma unroll
      for (int r = 0; r < 4; ++r)
        C[(size_t)(row + r) * N + col] = acc[mt][nt][r];
    }
}

// ---------- GEMM1 + fused RoPE v3: 2Mx2N interleaved-N waves, dbuf ----------
// Wave grid 2M x 2N with INTERLEAVED N-ownership: wave jn owns fragment-cols
// nt in {jn, jn+2, jn+4, jn+6}, so cols i and i+64 (nt and nt+4) stay in the
// same wave for the RoPE pairing, while B LDS reads drop 8->4 per h-step
// (each wave reads half the B-tile instead of all of it): 10 LDS reads per
// 16 MFMA -> 8, matching gemm_bt's proven ratio.
__global__ __launch_bounds__(256, 2) void gemm_rope_kernel(
    const unsigned short* __restrict__ A, const unsigned short* __restrict__ BT,
    const int* __restrict__ pos_ids, unsigned short* __restrict__ Qout) {
  __shared__ __align__(16) unsigned short As[2][128 * 64];
  __shared__ __align__(16) unsigned short Bs[2][128 * 64];
  const int tid = threadIdx.x;
  const int lane = tid & 63;
  const int wid = tid >> 6;
  const int jn = wid & 1;                 // N-wave index (interleaved cols)
  const int wm = (wid >> 1) * 64;         // M-wave offset
  const int g = blockIdx.x;
  const int xcd = g & 7, local = g >> 3;
  const int m0 = (xcd * 2 + (local & 1)) * 128;
  const int n0 = (local >> 1) * 128;
  const int lr = lane & 15;
  const int quad = lane >> 4;
  const int sw = lr & 7;
  const int nkt = HID >> 6;

  auto stage = [&](int buf, int kt) {
#pragma unroll
    for (int p = 0; p < 4; ++p) {
      const int c = p * 256 + tid;
      const int r = c >> 3, jsrc = (c & 7) ^ (r & 7);
      __builtin_amdgcn_global_load_lds(
          (const __attribute__((address_space(1))) void*)(A + (size_t)(m0 + r) * HID + kt * 64 + jsrc * 8),
          (__attribute__((address_space(3))) void*)(&As[buf][c * 8]), 16, 0, 0);
      __builtin_amdgcn_global_load_lds(
          (const __attribute__((address_space(1))) void*)(BT + (size_t)(n0 + r) * HID + kt * 64 + jsrc * 8),
          (__attribute__((address_space(3))) void*)(&Bs[buf][c * 8]), 16, 0, 0);
    }
  };

  f32x4 acc[4][4] = {};
  stage(0, 0);
  __syncthreads();
  int bufv = 0;
  for (int t = 0; t < nkt; ++t) {
    if (t + 1 < nkt) stage(bufv ^ 1, t + 1);
    const unsigned short* as = As[bufv];
    const unsigned short* bs = Bs[bufv];
#pragma unroll
    for (int h = 0; h < 2; ++h) {
      const int pos = ((h * 4 + quad) ^ sw) << 3;
      bf16x8 a[4], b[4];
#pragma unroll
      for (int tq = 0; tq < 4; ++tq) {
        a[tq] = *(const bf16x8*)(as + (wm + tq * 16 + lr) * 64 + pos);
        b[tq] = *(const bf16x8*)(bs + ((jn + 2 * tq) * 16 + lr) * 64 + pos);
      }
#pragma unroll
      for (int mt = 0; mt < 4; ++mt)
#pragma unroll
        for (int nt = 0; nt < 4; ++nt)
          acc[mt][nt] = __builtin_amdgcn_mfma_f32_16x16x32_bf16(a[mt], b[nt], acc[mt][nt], 0, 0, 0);
    }
    __syncthreads();
    bufv ^= 1;
  }
  // epilogue: acc[mt][t] holds cols (jn+2t)*16+lr; pair t with t+2 (= +64 cols)
  const int qd = quad << 2;
  const int h = n0 >> 7;
#pragma unroll
  for (int mt = 0; mt < 4; ++mt)
#pragma unroll
    for (int r = 0; r < 4; ++r) {
      const int row = m0 + wm + mt * 16 + qd + r;
      const float pos = (float)pos_ids[row];
#pragma unroll
      for (int t = 0; t < 2; ++t) {
        const int i = (jn + 2 * t) * 16 + lr;            // in [0,64)
        const float invf = __expf(-(float)(2 * i) * (9.2103403719761836f / 128.0f));
        float sn, cs;
        __sincosf(pos * invf, &sn, &cs);
        const float x1 = acc[mt][t][r], x2 = acc[mt][t + 2][r];
        Qout[((size_t)h * S_LEN + row) * HD + i]      = f2bf(x1 * cs - x2 * sn);
        Qout[((size_t)h * S_LEN + row) * HD + i + 64] = f2bf(x2 * cs + x1 * sn);
      }
    }
}

// ---------- flash attention v8: v5 structure + full chunk-XOR LDS swizzle ----------
// ONLY change vs round-4 (passing, 78us class): Ks/Vs/Ps strides become power-of-2
// (128/64/64 shorts) with the GEMM-proven 16B-chunk XOR (chunk ^= row&7) on both
// write and read sides. Targets the 6.1M SQ_LDS_BANK_CONFLICT cycles (~12% of
// attn runtime). Staging, barriers, softmax, epilogue byte-identical. LDS 53->48KB.
__global__ __launch_bounds__(256, 2) void attn_kernel(
    const unsigned short* __restrict__ Q, const unsigned short* __restrict__ Kc,
    const unsigned short* __restrict__ VT, unsigned short* __restrict__ Aout) {
  __shared__ __align__(16) unsigned short Ks[64 * 128];   // [skey][d], chunk-XOR
  __shared__ __align__(16) unsigned short Vs[128 * 64];   // [d][skey], chunk-XOR
  __shared__ __align__(16) unsigned short Ps[128 * 64];   // [qrow][skey], chunk-XOR
  const int tid = threadIdx.x, lane = tid & 63, wid = tid >> 6;
  const int qh = blockIdx.x;
  const int qt = (blockIdx.y < 8) ? (15 - (int)blockIdx.y) : ((int)blockIdx.y - 8);
  const int kvh = qh >> 2;
  const int lr = lane & 15, quad = lane >> 4;
  const int sw7 = lr & 7;
  const float SC = 0.12751619754705767f;   // (1/sqrt(128)) * log2(e)
  const float NB = -23.083120654223414f;   // -16 * log2(e)

  // Q fragments (B-operand: n=qrow=lane&15, k=d=quad*8+j)
  bf16x8 qf[2][4];
#pragma unroll
  for (int mt = 0; mt < 2; ++mt)
#pragma unroll
    for (int kk = 0; kk < 4; ++kk)
      qf[mt][kk] = *(const bf16x8*)(Q + ((size_t)qh * S_LEN + qt * 128 + wid * 32 + mt * 16 + lr) * HD + kk * 32 + quad * 8);

  f32x4 o[2][8] = {};        // O^T acc: row=d (quad*4+r within dt), col=qrow(lr)
  float lsum[2] = {0.f, 0.f};

  const int prow0 = (wid * 32 + lr) * 64;  // base for this lane's P rows (mt adds 16*64)
  const int nkt = 2 * qt + 2;
  for (int kt2 = 0; kt2 < nkt; ++kt2) {
    // global loads first (overlap previous iteration's compute)
    bf16x8 kr[4], vr[4];
#pragma unroll
    for (int p = 0; p < 4; ++p) {
      const int c = p * 256 + tid;
      kr[p] = *(const bf16x8*)(Kc + ((size_t)kvh * S_LEN + kt2 * 64 + (c >> 4)) * HD + (c & 15) * 8);
      vr[p] = *(const bf16x8*)(VT + ((size_t)kvh * HD + (c >> 3)) * S_LEN + kt2 * 64 + (c & 7) * 8);
    }
    __syncthreads();  // B1: all waves done reading Ks/Vs from prev iter
#pragma unroll
    for (int p = 0; p < 4; ++p) {
      const int c = p * 256 + tid;
      const int krow = c >> 4, kch = (c & 15) ^ (krow & 7);
      *(bf16x8*)(Ks + krow * 128 + kch * 8) = kr[p];
      const int vrow = c >> 3, vch = (c & 7) ^ (vrow & 7);
      *(bf16x8*)(Vs + vrow * 64 + vch * 8) = vr[p];
    }
    __syncthreads();  // B2: tiles staged

    const bool dtile = (kt2 >= 2 * qt);  // last two 64-key tiles intersect the diagonal
    // QK^T (transposed) + fused fixed-max softmax + packed P write
#pragma unroll
    for (int nt = 0; nt < 4; ++nt) {
      f32x4 s0 = {}, s1 = {};
#pragma unroll
      for (int kk = 0; kk < 4; ++kk) {
        bf16x8 kf = *(const bf16x8*)(Ks + (nt * 16 + lr) * 128 + (((kk * 4 + quad) ^ sw7) << 3));
        s0 = __builtin_amdgcn_mfma_f32_16x16x32_bf16(kf, qf[0][kk], s0, 0, 0, 0);
        s1 = __builtin_amdgcn_mfma_f32_16x16x32_bf16(kf, qf[1][kk], s1, 0, 0, 0);
      }
      const int skey0 = kt2 * 64 + nt * 16 + quad * 4;  // this lane's 4 consecutive keys
#pragma unroll
      for (int mt = 0; mt < 2; ++mt) {
        const f32x4 s = mt ? s1 : s0;
        const int qrow = qt * 128 + wid * 32 + mt * 16 + lr;
        float pv[4];
        float ls = 0.f;
#pragma unroll
        for (int r = 0; r < 4; ++r) {
          float v = fmaf(s[r], SC, NB);
          if (dtile && (skey0 + r) > qrow) v = -1e30f;
          pv[r] = exp2_fast(v);
          ls += pv[r];
        }
        lsum[mt] += ls;
        uint2 pk;
        pk.x = cvt_pk_bf16(pv[0], pv[1]);
        pk.y = cvt_pk_bf16(pv[2], pv[3]);
        // logical offset nt*16+quad*4 shorts = chunk (2nt + quad/2), sub (quad&1)*4
        *(uint2*)(Ps + prow0 + mt * 16 * 64 +
                  ((((2 * nt + (quad >> 1)) ^ sw7) << 3) + ((quad & 1) << 2))) = pk;
      }
    }
    // PV: O^T += V^T · P^T  (wave-local P rows; in-wave LDS ordering, no barrier)
    bf16x8 pf[2][2];
#pragma unroll
    for (int mt = 0; mt < 2; ++mt)
#pragma unroll
      for (int kk = 0; kk < 2; ++kk)
        pf[mt][kk] = *(const bf16x8*)(Ps + prow0 + mt * 16 * 64 + (((kk * 4 + quad) ^ sw7) << 3));
#pragma unroll
    for (int dt = 0; dt < 8; ++dt)
#pragma unroll
      for (int kk = 0; kk < 2; ++kk) {
        bf16x8 vf = *(const bf16x8*)(Vs + (dt * 16 + lr) * 64 + (((kk * 4 + quad) ^ sw7) << 3));
        o[0][dt] = __builtin_amdgcn_mfma_f32_16x16x32_bf16(vf, pf[0][kk], o[0][dt], 0, 0, 0);
        o[1][dt] = __builtin_amdgcn_mfma_f32_16x16x32_bf16(vf, pf[1][kk], o[1][dt], 0, 0, 0);
      }
  }

  // epilogue: reduce lsum over the 4 lanes sharing each qrow (quad axis), scale, store
#pragma unroll
  for (int mt = 0; mt < 2; ++mt) {
    float l = lsum[mt];
    l += __shfl_xor(l, 16);
    l += __shfl_xor(l, 32);
    const float inv = 1.0f / l;
    const int qrow = qt * 128 + wid * 32 + mt * 16 + lr;
#pragma unroll
    for (int dt = 0; dt < 8; ++dt) {
      uint2 w;
      w.x = cvt_pk_bf16(o[mt][dt][0] * inv, o[mt][dt][1] * inv);
      w.y = cvt_pk_bf16(o[mt][dt][2] * inv, o[mt][dt][3] * inv);
      *(uint2*)(Aout + (size_t)qrow * HID + qh * HD + dt * 16 + quad * 4) = w;
    }
  }
}

extern "C" void kernel_launch(void* const* d_in, const int* in_sizes, int n_in,
                              void* d_out, int out_size, void* d_ws, size_t ws_size,
                              hipStream_t stream) {
  const float* hidden  = (const float*)d_in[0];   // [1][2048][4096]
  const float* k_cache = (const float*)d_in[1];   // [1][8][2048][128]
  const float* v_cache = (const float*)d_in[2];   // [1][8][2048][128]
  const float* Wq      = (const float*)d_in[3];   // [4096][4096]
  const float* Wo      = (const float*)d_in[4];   // [4096][4096]
  const int*   pos     = (const int*)d_in[5];     // [1][2048]
  float* out = (float*)d_out;

  char* ws = (char*)d_ws;
  unsigned short* hidden_bf = (unsigned short*)(ws + 0);            // 16 MB
  unsigned short* attn_bf   = hidden_bf;                            // alias (hidden dead after GEMM1)
  unsigned short* WqT       = (unsigned short*)(ws + 16777216);     // 32 MB
  unsigned short* WoT       = (unsigned short*)(ws + 50331648);     // 32 MB
  unsigned short* k_bf      = (unsigned short*)(ws + 83886080);     // 4 MB
  unsigned short* vT        = (unsigned short*)(ws + 88080384);     // 4 MB
  unsigned short* q_bf      = (unsigned short*)(ws + 92274688);     // 16 MB

  cvt2_bf16_kernel<<<10240, 256, 0, stream>>>(hidden, hidden_bf, k_cache, k_bf);
  transpose_cvt3_kernel<<<dim3(64, 64, 3), 256, 0, stream>>>(Wq, WqT, Wo, WoT, v_cache, vT);

  gemm_rope_kernel<<<dim3((S_LEN / 128) * (HID / 128)), 256, 0, stream>>>(hidden_bf, WqT, pos, q_bf);
  attn_kernel<<<dim3(NH, S_LEN / 128), 256, 0, stream>>>(q_bf, k_bf, vT, attn_bf);
  gemm_bt_kernel<<<dim3((S_LEN / 128) * (HID / 128)), 256, 0, stream>>>(attn_bf, WoT, out, S_LEN, HID, HID);
}